// Round 9
// baseline (225.113 us; speedup 1.0000x reference)
//
#include <hip/hip_runtime.h>
#include <hip/hip_bf16.h>
#include <cstdint>

#define KD 512
#define BM 64
#define NT 256
#define NSPLIT 63
#define NNODES 127

typedef __attribute__((ext_vector_type(8))) short bf16x8;
typedef __attribute__((ext_vector_type(4))) float f32x4;

#define MFMA_B16(a, b, c) __builtin_amdgcn_mfma_f32_16x16x32_bf16(a, b, c, 0, 0, 0)
#define SCHED_FENCE() __builtin_amdgcn_sched_barrier(0)

static __device__ __forceinline__ unsigned short f2bf(float f) {
    return __builtin_bit_cast(unsigned short, __float2bfloat16(f));
}
static __device__ __forceinline__ float bf2f(unsigned short h) {
    return __builtin_bit_cast(float, (unsigned)h << 16);
}
static __device__ __forceinline__ unsigned pack2(float f0, float f1) {
    return (unsigned)f2bf(f0) | ((unsigned)f2bf(f1) << 16);
}

// 8 fp32 -> bf16 hi8 + residual lo8; named scalars only (stays in VGPRs)
static __device__ __forceinline__ void cvt8(f32x4 a, f32x4 b, bf16x8& hi, bf16x8& lo) {
    const unsigned short h0 = f2bf(a[0]), h1 = f2bf(a[1]), h2 = f2bf(a[2]), h3 = f2bf(a[3]);
    const unsigned short h4 = f2bf(b[0]), h5 = f2bf(b[1]), h6 = f2bf(b[2]), h7 = f2bf(b[3]);
    uint4 H = make_uint4((unsigned)h0 | ((unsigned)h1 << 16), (unsigned)h2 | ((unsigned)h3 << 16),
                         (unsigned)h4 | ((unsigned)h5 << 16), (unsigned)h6 | ((unsigned)h7 << 16));
    uint4 L = make_uint4(pack2(a[0] - bf2f(h0), a[1] - bf2f(h1)),
                         pack2(a[2] - bf2f(h2), a[3] - bf2f(h3)),
                         pack2(b[0] - bf2f(h4), b[1] - bf2f(h5)),
                         pack2(b[2] - bf2f(h6), b[3] - bf2f(h7)));
    hi = __builtin_bit_cast(bf16x8, H);
    lo = __builtin_bit_cast(bf16x8, L);
}

static __device__ __forceinline__ void gload_lds16(const float* g, void* l) {
    __builtin_amdgcn_global_load_lds(
        (const __attribute__((address_space(1))) unsigned int*)g,
        (__attribute__((address_space(3))) unsigned int*)l, 16, 0, 0);
}

template<int N> static __device__ __forceinline__ void vmwait() {
    if constexpr (N == 10)     asm volatile("s_waitcnt vmcnt(10)" ::: "memory");
    else if constexpr (N == 2) asm volatile("s_waitcnt vmcnt(2)" ::: "memory");
    else                       asm volatile("s_waitcnt vmcnt(0)" ::: "memory");
}

// DFS path-min; lane part8 stores clipped nodes [part8*16, part8*16+16)
template<int T>
static __device__ __forceinline__ void tree_walk8(float qt, const float* __restrict__ srow,
                                                  float* __restrict__ zrow, int part8) {
    const float s  = srow[T];
    const float ql = fminf(qt, s);
    const float qr = fminf(qt, -s);
    if (((2 * T + 1) >> 4) == part8) zrow[2 * T + 1] = fminf(fmaxf(ql, 0.f), 1.f);
    if (((2 * T + 2) >> 4) == part8) zrow[2 * T + 2] = fminf(fmaxf(qr, 0.f), 1.f);
    if constexpr (2 * T + 1 < NSPLIT) tree_walk8<2 * T + 1>(ql, srow, zrow, part8);
    if constexpr (2 * T + 2 < NSPLIT) tree_walk8<2 * T + 2>(qr, srow, zrow, part8);
}

// ---------------- prep: A (63x512 fp32) -> bf16 hi/lo planes [64][512] in ws
__global__ __launch_bounds__(256)
void lt_prep(const float* __restrict__ A, unsigned short* __restrict__ ws) {
    const int gid = blockIdx.x * 256 + threadIdx.x;   // 8192 total
    const int row = gid >> 7;                         // 0..63
    const int c4  = (gid & 127) << 2;                 // 0..508
    f32x4 v = (f32x4)(0.f);
    if (row < NSPLIT)
        v = *reinterpret_cast<const f32x4*>(A + (size_t)row * KD + c4);
    const unsigned short h0 = f2bf(v[0]), h1 = f2bf(v[1]), h2 = f2bf(v[2]), h3 = f2bf(v[3]);
    uint2 hv = make_uint2((unsigned)h0 | ((unsigned)h1 << 16),
                          (unsigned)h2 | ((unsigned)h3 << 16));
    uint2 lv = make_uint2(pack2(v[0] - bf2f(h0), v[1] - bf2f(h1)),
                          pack2(v[2] - bf2f(h2), v[3] - bf2f(h3)));
    *reinterpret_cast<uint2*>(ws + row * KD + c4)         = hv;   // hi plane
    *reinterpret_cast<uint2*>(ws + 32768 + row * KD + c4) = lv;   // lo plane
}

// ---------------- main K-step, fully compile-time, ZERO block barriers
// vm-queue invariant at entry (T>=1): [x_{T+1}(2)]; x_T already drained.
template<int T>
static __device__ __forceinline__ void tiles(
        const float* xsrc, unsigned char* xw, const unsigned short* bwsl,
        int va_off, f32x4 (&acc)[4]) {
    // group 1: B_T fragment loads, straight to regs as bf16 (L2-hot)
    const unsigned short* bp = bwsl + T * 32;
    bf16x8 bh0 = *reinterpret_cast<const bf16x8*>(bp);
    bf16x8 bh1 = *reinterpret_cast<const bf16x8*>(bp + 8192);
    bf16x8 bh2 = *reinterpret_cast<const bf16x8*>(bp + 16384);
    bf16x8 bh3 = *reinterpret_cast<const bf16x8*>(bp + 24576);
    bf16x8 bl0 = *reinterpret_cast<const bf16x8*>(bp + 32768);
    bf16x8 bl1 = *reinterpret_cast<const bf16x8*>(bp + 40960);
    bf16x8 bl2 = *reinterpret_cast<const bf16x8*>(bp + 49152);
    bf16x8 bl3 = *reinterpret_cast<const bf16x8*>(bp + 57344);
    SCHED_FENCE();
    // group 2: x_T fragments from wave-private LDS buf (DMA drained: see invariant)
    if constexpr (T == 0) vmwait<10>();          // drain x0 (queue [x0,x1,B0])
    const unsigned char* xbf = xw + (T % 3) * 2048;
    f32x4 va = *reinterpret_cast<const f32x4*>(xbf + va_off);
    f32x4 vb = *reinterpret_cast<const f32x4*>(xbf + (va_off ^ 16));
    SCHED_FENCE();
    // group 3: issue x_{T+2} DMA into buf (T+2)%3 (reads of that buf done at T-1)
    if constexpr (T + 2 < 16) {
        unsigned char* nb = xw + ((T + 2) % 3) * 2048;
        gload_lds16(xsrc + (T + 2) * 32, nb);
        gload_lds16(xsrc + (T + 2) * 32 + 4096, nb + 1024);
    }
    SCHED_FENCE();
    // queue now [x_{T+1}(2), B_T(8), x_{T+2}(2)] -> vmcnt(2) drains x_{T+1}+B_T
    vmwait<(T + 2 < 16) ? 2 : 0>();
    SCHED_FENCE();

    bf16x8 ah, al;
    cvt8(va, vb, ah, al);
    acc[0] = MFMA_B16(ah, bh0, acc[0]);
    acc[1] = MFMA_B16(ah, bh1, acc[1]);
    acc[2] = MFMA_B16(ah, bh2, acc[2]);
    acc[3] = MFMA_B16(ah, bh3, acc[3]);
    acc[0] = MFMA_B16(al, bh0, acc[0]);
    acc[1] = MFMA_B16(al, bh1, acc[1]);
    acc[2] = MFMA_B16(al, bh2, acc[2]);
    acc[3] = MFMA_B16(al, bh3, acc[3]);
    acc[0] = MFMA_B16(ah, bl0, acc[0]);
    acc[1] = MFMA_B16(ah, bl1, acc[1]);
    acc[2] = MFMA_B16(ah, bl2, acc[2]);
    acc[3] = MFMA_B16(ah, bl3, acc[3]);

    if constexpr (T + 1 < 16)
        tiles<T + 1>(xsrc, xw, bwsl, va_off, acc);
}

// LDS: 4 waves x 3 bufs x 2048 B = 24576 -> 6 blocks/CU = 24 waves/CU.
__global__ __launch_bounds__(NT, 6)
void lt_mfma8(const float* __restrict__ x, const unsigned short* __restrict__ bws,
              float* __restrict__ out) {
    __shared__ __align__(16) unsigned char lds[24576];

    const int tid  = threadIdx.x;
    const int wave = tid >> 6;
    const int lane = tid & 63;
    const int fr   = lane & 15;
    const int g    = lane >> 4;
    const int r0   = blockIdx.x * BM;

    unsigned char* xw = lds + wave * 6144;
    // x source: row = r0 + wave*16 + j*8 + (lane>>3); col slot pre-swizzled (linear LDS)
    const float* xsrc = x + (size_t)(r0 + wave * 16 + (lane >> 3)) * KD
                          + (((lane & 7) ^ ((lane >> 3) & 7)) << 2);
    // per-lane B pointer (ushort units): row = nf*16+fr (stride 8192=16*512), k base g*8
    const unsigned short* bwsl = bws + fr * KD + g * 8;
    // x frag: row fr, slots (2g)^m / +hi, m = fr&7
    const int va_off = (fr << 7) + (((g << 1) ^ (fr & 7)) << 4);

    f32x4 acc[4];
#pragma unroll
    for (int j = 0; j < 4; ++j) acc[j] = (f32x4)(0.f);

    // prologue: issue x0, x1 DMAs (queue [x0(2), x1(2)])
    gload_lds16(xsrc, xw);
    gload_lds16(xsrc + 4096, xw + 1024);
    gload_lds16(xsrc + 32, xw + 2048);
    gload_lds16(xsrc + 32 + 4096, xw + 3072);
    SCHED_FENCE();

    tiles<0>(xsrc, xw, bwsl, va_off, acc);

    // ---- epilogue: wave-private 6144 B = warea[8][65] (2080) + zw[8][127] (4064)
    float* warea = reinterpret_cast<float*>(xw);
    float* zw    = warea + 520;
    const int o  = lane >> 3;                  // row 0..7
    const int p8 = lane & 7;                   // nodes [p8*16, p8*16+16)

#pragma unroll
    for (int s = 0; s < 2; ++s) {
        if ((g >> 1) == s) {                   // rows 8s..8s+7 live in g in {2s,2s+1}
#pragma unroll
            for (int nf = 0; nf < 4; ++nf)
#pragma unroll
                for (int rg = 0; rg < 4; ++rg)
                    warea[((g & 1) * 4 + rg) * 65 + nf * 16 + fr] = acc[nf][rg];
        }
        // same-wave LDS ordering via lgkmcnt (compiler-tracked); no barrier
        const float* srow = warea + o * 65;
        float* zrow = zw + o * NNODES;
        if (p8 == 0) zrow[0] = 1.f;
        tree_walk8<0>(1.f, srow, zrow, p8);

        float* og = out + (size_t)(r0 + wave * 16 + s * 8) * NNODES;
#pragma unroll
        for (int j = 0; j < 4; ++j) {
            const int idx = j * 64 + lane;
            if (idx < 254)
                *reinterpret_cast<f32x4*>(og + idx * 4) =
                    *reinterpret_cast<const f32x4*>(zw + idx * 4);
        }
    }
}

extern "C" void kernel_launch(void* const* d_in, const int* in_sizes, int n_in,
                              void* d_out, int out_size, void* d_ws, size_t ws_size,
                              hipStream_t stream) {
    const float* x = (const float*)d_in[0];          // [131072, 512]
    const float* A = (const float*)d_in[1];          // [63, 512]
    float* out = (float*)d_out;                      // [131072, 127]
    unsigned short* ws = (unsigned short*)d_ws;      // 128 KB: B bf16 hi/lo planes
    const int nrows = in_sizes[0] / KD;              // 131072
    lt_prep<<<dim3(32), dim3(256), 0, stream>>>(A, ws);
    lt_mfma8<<<dim3(nrows / BM), dim3(NT), 0, stream>>>(x, ws, out);
}

// Round 10
// 96.846 us; speedup vs baseline: 2.3244x; 2.3244x over previous
//
#include <hip/hip_runtime.h>
#include <hip/hip_bf16.h>
#include <cstdint>

#define KD 512
#define BM 128
#define NT 512
#define NSPLIT 63
#define NNODES 127
#define B_OFF 32768        // block B region: 2 bufs x (hi 4KB + lo 4KB) = 16 KB

typedef __attribute__((ext_vector_type(8))) short bf16x8;
typedef __attribute__((ext_vector_type(4))) float f32x4;

#define MFMA_B16(a, b, c) __builtin_amdgcn_mfma_f32_16x16x32_bf16(a, b, c, 0, 0, 0)
#define SCHED_FENCE() __builtin_amdgcn_sched_barrier(0)

static __device__ __forceinline__ unsigned short f2bf(float f) {
    return __builtin_bit_cast(unsigned short, __float2bfloat16(f));
}
static __device__ __forceinline__ float bf2f(unsigned short h) {
    return __builtin_bit_cast(float, (unsigned)h << 16);
}
static __device__ __forceinline__ unsigned pack2(float f0, float f1) {
    return (unsigned)f2bf(f0) | ((unsigned)f2bf(f1) << 16);
}

// 8 fp32 -> bf16 hi8 + residual lo8; named scalars only (stays in VGPRs)
static __device__ __forceinline__ void cvt8(f32x4 a, f32x4 b, bf16x8& hi, bf16x8& lo) {
    const unsigned short h0 = f2bf(a[0]), h1 = f2bf(a[1]), h2 = f2bf(a[2]), h3 = f2bf(a[3]);
    const unsigned short h4 = f2bf(b[0]), h5 = f2bf(b[1]), h6 = f2bf(b[2]), h7 = f2bf(b[3]);
    uint4 H = make_uint4((unsigned)h0 | ((unsigned)h1 << 16), (unsigned)h2 | ((unsigned)h3 << 16),
                         (unsigned)h4 | ((unsigned)h5 << 16), (unsigned)h6 | ((unsigned)h7 << 16));
    uint4 L = make_uint4(pack2(a[0] - bf2f(h0), a[1] - bf2f(h1)),
                         pack2(a[2] - bf2f(h2), a[3] - bf2f(h3)),
                         pack2(b[0] - bf2f(h4), b[1] - bf2f(h5)),
                         pack2(b[2] - bf2f(h6), b[3] - bf2f(h7)));
    hi = __builtin_bit_cast(bf16x8, H);
    lo = __builtin_bit_cast(bf16x8, L);
}

static __device__ __forceinline__ void gload_lds16(const void* g, void* l) {
    __builtin_amdgcn_global_load_lds(
        (const __attribute__((address_space(1))) unsigned int*)g,
        (__attribute__((address_space(3))) unsigned int*)l, 16, 0, 0);
}

template<int N> static __device__ __forceinline__ void vmwait() {
    if constexpr (N == 2) asm volatile("s_waitcnt vmcnt(2)" ::: "memory");
    else                  asm volatile("s_waitcnt vmcnt(0)" ::: "memory");
}

// DFS path-min; lane part16 stores clipped nodes [part16*8, part16*8+8)
template<int T>
static __device__ __forceinline__ void tree_walk16(float qt, const float* __restrict__ srow,
                                                   float* __restrict__ zrow, int part16) {
    const float s  = srow[T];
    const float ql = fminf(qt, s);
    const float qr = fminf(qt, -s);
    if (((2 * T + 1) >> 3) == part16) zrow[2 * T + 1] = fminf(fmaxf(ql, 0.f), 1.f);
    if (((2 * T + 2) >> 3) == part16) zrow[2 * T + 2] = fminf(fmaxf(qr, 0.f), 1.f);
    if constexpr (2 * T + 1 < NSPLIT) tree_walk16<2 * T + 1>(ql, srow, zrow, part16);
    if constexpr (2 * T + 2 < NSPLIT) tree_walk16<2 * T + 2>(qr, srow, zrow, part16);
}

// ---------------- prep: A (63x512 fp32) -> bf16 hi/lo planes [64][512] in ws
__global__ __launch_bounds__(256)
void lt_prep(const float* __restrict__ A, unsigned short* __restrict__ ws) {
    const int gid = blockIdx.x * 256 + threadIdx.x;   // 8192 total
    const int row = gid >> 7;                         // 0..63
    const int c4  = (gid & 127) << 2;                 // 0..508
    f32x4 v = (f32x4)(0.f);
    if (row < NSPLIT)
        v = *reinterpret_cast<const f32x4*>(A + (size_t)row * KD + c4);
    const unsigned short h0 = f2bf(v[0]), h1 = f2bf(v[1]), h2 = f2bf(v[2]), h3 = f2bf(v[3]);
    uint2 hv = make_uint2((unsigned)h0 | ((unsigned)h1 << 16),
                          (unsigned)h2 | ((unsigned)h3 << 16));
    uint2 lv = make_uint2(pack2(v[0] - bf2f(h0), v[1] - bf2f(h1)),
                          pack2(v[2] - bf2f(h2), v[3] - bf2f(h3)));
    *reinterpret_cast<uint2*>(ws + row * KD + c4)         = hv;   // hi plane
    *reinterpret_cast<uint2*>(ws + 32768 + row * KD + c4) = lv;   // lo plane
}

// ---------------- main K-step: 1 barrier/tile, counted vmcnt(2), all DMA staging
template<int T>
static __device__ __forceinline__ void tiles(
        const float* xsrc, const unsigned short* bsrc,
        unsigned char* xw, unsigned char* bB, int bdoff,
        int va_off, int bo, f32x4 (&acc)[4]) {
    // (1) issue B chunk T+1 DMA into the other B buffer (1 instr/wave)
    if constexpr (T + 1 < 16)
        gload_lds16(bsrc + (T + 1) * 32, bB + ((T + 1) & 1) * 8192 + bdoff);
    SCHED_FENCE();
    // (2) frag reads: x (2 b128) + B hi (4 b128); then drain lgkm (buf reuse below)
    const unsigned char* xbf = xw + (T & 1) * 2048;
    f32x4 va = *reinterpret_cast<const f32x4*>(xbf + va_off);
    f32x4 vb = *reinterpret_cast<const f32x4*>(xbf + (va_off ^ 16));
    const unsigned char* bb = bB + (T & 1) * 8192;
    bf16x8 bh0 = *reinterpret_cast<const bf16x8*>(bb + bo);
    bf16x8 bh1 = *reinterpret_cast<const bf16x8*>(bb + bo + 1024);
    bf16x8 bh2 = *reinterpret_cast<const bf16x8*>(bb + bo + 2048);
    bf16x8 bh3 = *reinterpret_cast<const bf16x8*>(bb + bo + 3072);
    asm volatile("s_waitcnt lgkmcnt(0)" ::: "memory");
    SCHED_FENCE();
    // (3) issue x tile T+2 DMA into the buffer we just finished reading
    if constexpr (T + 2 < 16) {
        gload_lds16(xsrc + (T + 2) * 32, xw + (T & 1) * 2048);
        gload_lds16(xsrc + (T + 2) * 32 + 8 * KD, xw + (T & 1) * 2048 + 1024);
    }
    SCHED_FENCE();
    // (4) compute: hh + lh with hi-plane frags, then hl with lo-plane frags
    bf16x8 ah, al;
    cvt8(va, vb, ah, al);
    acc[0] = MFMA_B16(ah, bh0, acc[0]);
    acc[1] = MFMA_B16(ah, bh1, acc[1]);
    acc[2] = MFMA_B16(ah, bh2, acc[2]);
    acc[3] = MFMA_B16(ah, bh3, acc[3]);
    acc[0] = MFMA_B16(al, bh0, acc[0]);
    acc[1] = MFMA_B16(al, bh1, acc[1]);
    acc[2] = MFMA_B16(al, bh2, acc[2]);
    acc[3] = MFMA_B16(al, bh3, acc[3]);
    bf16x8 bl0 = *reinterpret_cast<const bf16x8*>(bb + 4096 + bo);
    bf16x8 bl1 = *reinterpret_cast<const bf16x8*>(bb + 4096 + bo + 1024);
    bf16x8 bl2 = *reinterpret_cast<const bf16x8*>(bb + 4096 + bo + 2048);
    bf16x8 bl3 = *reinterpret_cast<const bf16x8*>(bb + 4096 + bo + 3072);
    acc[0] = MFMA_B16(ah, bl0, acc[0]);
    acc[1] = MFMA_B16(ah, bl1, acc[1]);
    acc[2] = MFMA_B16(ah, bl2, acc[2]);
    acc[3] = MFMA_B16(ah, bl3, acc[3]);
    // (5) counted drain: x_{T+1}+B_{T+1} landed, x_{T+2} stays in flight; barrier
    if constexpr (T + 1 < 16) {
        SCHED_FENCE();
        vmwait<(T + 2 < 16) ? 2 : 0>();
        SCHED_FENCE();
        __builtin_amdgcn_s_barrier();
        tiles<T + 1>(xsrc, bsrc, xw, bB, bdoff, va_off, bo, acc);
    }
}

// LDS 49152 B: x = 8 waves x (2 x 2048) = 32 KB; B = 2 bufs x (hi 4K + lo 4K) = 16 KB.
// 3 blocks/CU (144 KB) = 24 waves/CU = 6 waves/SIMD.
__global__ __launch_bounds__(NT, 6)
void lt_mfma9(const float* __restrict__ x, const unsigned short* __restrict__ ws,
              float* __restrict__ out) {
    __shared__ __align__(16) unsigned char lds[49152];
    unsigned char* bB = lds + B_OFF;

    const int tid  = threadIdx.x;
    const int wave = tid >> 6;
    const int lane = tid & 63;
    const int fr   = lane & 15;
    const int g    = lane >> 4;
    const int r0   = blockIdx.x * BM;

    unsigned char* xw = lds + wave * 4096;                // wave-private x dbuf
    // x DMA source: row = r0 + wave*16 + j*8 + (lane>>3); slot pre-swizzled (linear dest)
    const float* xsrc = x + (size_t)(r0 + wave * 16 + (lane >> 3)) * KD
                          + (((lane & 7) ^ ((lane >> 3) & 7)) << 2);
    // B DMA: wave -> (plane p, quarter qq); row = qq*16 + (lane>>2); slot swizzled on src
    const int p  = wave >> 2;
    const int qq = wave & 3;
    {
    }
    const int brow = qq * 16 + (lane >> 2);
    const unsigned short* bsrc = ws + p * 32768 + brow * KD
                                    + (((lane & 3) ^ (brow & 3)) << 3);
    const int bdoff = p * 4096 + qq * 1024;
    // frag offsets
    const int va_off = (fr << 7) + (((g << 1) ^ (fr & 7)) << 4);          // x: row fr
    const int bo     = (fr << 6) + ((g ^ (fr & 3)) << 4);                 // B: +nf*1024

    f32x4 acc[4];
#pragma unroll
    for (int j = 0; j < 4; ++j) acc[j] = (f32x4)(0.f);

    // prologue: B0, x0, x1 DMAs; vmcnt(2) leaves x1 in flight; barrier
    gload_lds16(bsrc, bB + bdoff);
    gload_lds16(xsrc, xw);
    gload_lds16(xsrc + 8 * KD, xw + 1024);
    gload_lds16(xsrc + 32, xw + 2048);
    gload_lds16(xsrc + 32 + 8 * KD, xw + 3072);
    SCHED_FENCE();
    vmwait<2>();
    SCHED_FENCE();
    __builtin_amdgcn_s_barrier();

    tiles<0>(xsrc, bsrc, xw, bB, bdoff, va_off, bo, acc);

    // ---- epilogue: fully wave-private (own 4 KB x region), 4 sub-phases of 4 rows
    float* warea = reinterpret_cast<float*>(xw);          // [4][65]  = 1040 B
    float* zw    = warea + 260;                           // [4][127] = 2032 B (16B-aligned)
    const int o      = lane >> 4;                         // row 0..3
    const int part16 = lane & 15;                         // nodes [part16*8, +8)

#pragma unroll
    for (int s = 0; s < 4; ++s) {
        if (g == s) {
#pragma unroll
            for (int nf = 0; nf < 4; ++nf)
#pragma unroll
                for (int rg = 0; rg < 4; ++rg)
                    warea[rg * 65 + nf * 16 + fr] = acc[nf][rg];
        }
        // same-wave LDS ordering via lgkmcnt; no barriers
        const float* srow = warea + o * 65;
        float* zrow = zw + o * NNODES;
        if (part16 == 0) zrow[0] = 1.f;
        tree_walk16<0>(1.f, srow, zrow, part16);

        float* og = out + (size_t)(r0 + wave * 16 + s * 4) * NNODES;  // 2032B-aligned
#pragma unroll
        for (int j = 0; j < 2; ++j) {
            const int idx = j * 64 + lane;
            if (idx < 127)
                *reinterpret_cast<f32x4*>(og + idx * 4) =
                    *reinterpret_cast<const f32x4*>(zw + idx * 4);
        }
    }
}

extern "C" void kernel_launch(void* const* d_in, const int* in_sizes, int n_in,
                              void* d_out, int out_size, void* d_ws, size_t ws_size,
                              hipStream_t stream) {
    const float* x = (const float*)d_in[0];          // [131072, 512]
    const float* A = (const float*)d_in[1];          // [63, 512]
    float* out = (float*)d_out;                      // [131072, 127]
    unsigned short* ws = (unsigned short*)d_ws;      // 128 KB: B bf16 hi/lo planes
    const int nrows = in_sizes[0] / KD;              // 131072
    lt_prep<<<dim3(32), dim3(256), 0, stream>>>(A, ws);
    lt_mfma9<<<dim3(nrows / BM), dim3(NT), 0, stream>>>(x, ws, out);
}

// Round 11
// 82.211 us; speedup vs baseline: 2.7383x; 1.1780x over previous
//
#include <hip/hip_runtime.h>
#include <hip/hip_bf16.h>
#include <cstdint>

#define KD 512
#define BM 128
#define NT 512
#define NSPLIT 63
#define NNODES 127
#define XB 6144            // per-wave x region: 3 bufs x 2048 B; 8 waves = 48 KB
#define B_OFF 49152        // B dbuf: 2 x (hi 8 KB + lo 8 KB) = 32 KB; total 80 KB

typedef __attribute__((ext_vector_type(8))) short bf16x8;
typedef __attribute__((ext_vector_type(4))) float f32x4;

#define MFMA_B16(a, b, c) __builtin_amdgcn_mfma_f32_16x16x32_bf16(a, b, c, 0, 0, 0)
#define SCHED_FENCE() __builtin_amdgcn_sched_barrier(0)

static __device__ __forceinline__ unsigned short f2bf(float f) {
    return __builtin_bit_cast(unsigned short, __float2bfloat16(f));
}
static __device__ __forceinline__ float bf2f(unsigned short h) {
    return __builtin_bit_cast(float, (unsigned)h << 16);
}
static __device__ __forceinline__ unsigned pack2(float f0, float f1) {
    return (unsigned)f2bf(f0) | ((unsigned)f2bf(f1) << 16);
}

// 8 fp32 -> bf16 hi8 + residual lo8; named scalars only (stays in VGPRs)
static __device__ __forceinline__ void cvt8(f32x4 a, f32x4 b, bf16x8& hi, bf16x8& lo) {
    const unsigned short h0 = f2bf(a[0]), h1 = f2bf(a[1]), h2 = f2bf(a[2]), h3 = f2bf(a[3]);
    const unsigned short h4 = f2bf(b[0]), h5 = f2bf(b[1]), h6 = f2bf(b[2]), h7 = f2bf(b[3]);
    uint4 H = make_uint4((unsigned)h0 | ((unsigned)h1 << 16), (unsigned)h2 | ((unsigned)h3 << 16),
                         (unsigned)h4 | ((unsigned)h5 << 16), (unsigned)h6 | ((unsigned)h7 << 16));
    uint4 L = make_uint4(pack2(a[0] - bf2f(h0), a[1] - bf2f(h1)),
                         pack2(a[2] - bf2f(h2), a[3] - bf2f(h3)),
                         pack2(b[0] - bf2f(h4), b[1] - bf2f(h5)),
                         pack2(b[2] - bf2f(h6), b[3] - bf2f(h7)));
    hi = __builtin_bit_cast(bf16x8, H);
    lo = __builtin_bit_cast(bf16x8, L);
}

static __device__ __forceinline__ void gload_lds16(const void* g, void* l) {
    __builtin_amdgcn_global_load_lds(
        (const __attribute__((address_space(1))) unsigned int*)g,
        (__attribute__((address_space(3))) unsigned int*)l, 16, 0, 0);
}

template<int N> static __device__ __forceinline__ void vmwait() {
    if constexpr (N == 6)      asm volatile("s_waitcnt vmcnt(6)" ::: "memory");
    else if constexpr (N == 4) asm volatile("s_waitcnt vmcnt(4)" ::: "memory");
    else if constexpr (N == 2) asm volatile("s_waitcnt vmcnt(2)" ::: "memory");
    else                       asm volatile("s_waitcnt vmcnt(0)" ::: "memory");
}

// DFS path-min; lane p8 stores clipped nodes [p8*16, p8*16+16)
template<int T>
static __device__ __forceinline__ void tree_walk8(float qt, const float* __restrict__ srow,
                                                  float* __restrict__ zrow, int p8) {
    const float s  = srow[T];
    const float ql = fminf(qt, s);
    const float qr = fminf(qt, -s);
    if (((2 * T + 1) >> 4) == p8) zrow[2 * T + 1] = fminf(fmaxf(ql, 0.f), 1.f);
    if (((2 * T + 2) >> 4) == p8) zrow[2 * T + 2] = fminf(fmaxf(qr, 0.f), 1.f);
    if constexpr (2 * T + 1 < NSPLIT) tree_walk8<2 * T + 1>(ql, srow, zrow, p8);
    if constexpr (2 * T + 2 < NSPLIT) tree_walk8<2 * T + 2>(qr, srow, zrow, p8);
}

// ---------------- prep: A (63x512 fp32) -> bf16 hi/lo planes [64][512] in ws
__global__ __launch_bounds__(256)
void lt_prep(const float* __restrict__ A, unsigned short* __restrict__ ws) {
    const int gid = blockIdx.x * 256 + threadIdx.x;   // 8192 total
    const int row = gid >> 7;                         // 0..63
    const int c4  = (gid & 127) << 2;                 // 0..508
    f32x4 v = (f32x4)(0.f);
    if (row < NSPLIT)
        v = *reinterpret_cast<const f32x4*>(A + (size_t)row * KD + c4);
    const unsigned short h0 = f2bf(v[0]), h1 = f2bf(v[1]), h2 = f2bf(v[2]), h3 = f2bf(v[3]);
    uint2 hv = make_uint2((unsigned)h0 | ((unsigned)h1 << 16),
                          (unsigned)h2 | ((unsigned)h3 << 16));
    uint2 lv = make_uint2(pack2(v[0] - bf2f(h0), v[1] - bf2f(h1)),
                          pack2(v[2] - bf2f(h2), v[3] - bf2f(h3)));
    *reinterpret_cast<uint2*>(ws + row * KD + c4)         = hv;   // hi plane
    *reinterpret_cast<uint2*>(ws + 32768 + row * KD + c4) = lv;   // lo plane
}

// ---------------- one 32-k tile. Sync pattern (m201): counted own-wave vmcnt
// BEFORE raw s_barrier; x prefetch (depth 2) never drained in the main loop.
// Per-wave issue order: even tile: B_{c+1}(2), x_{T+2}(2); odd tile: x_{T+2}(2).
// vm_pre=4 retires own B_c only; vm_read=6 retires x_T only (hand-verified T=0..15).
template<int T>
static __device__ __forceinline__ void tiles(
        const float* xsrc, const unsigned short* bsrc,
        unsigned char* xw, unsigned char* bB, int bdoff,
        int va_off, int bo0, int bo1, f32x4 (&acc)[4]) {
    if constexpr ((T & 1) == 0) {
        SCHED_FENCE();
        vmwait<4>();                       // own 2 B_c loads drained; x stays in flight
        SCHED_FENCE();
        __builtin_amdgcn_s_barrier();      // all waves' B_c landed; B_{c-1} buf free
        SCHED_FENCE();
        if constexpr (T / 2 + 1 < 8) {     // issue B_{c+1} DMA (2 instrs/wave)
            const unsigned short* bs = bsrc + (T / 2 + 1) * 64;
            unsigned char* bd = bB + ((T / 2 + 1) & 1) * 16384 + bdoff;
            gload_lds16(bs, bd);
            gload_lds16(bs + 8 * KD, bd + 1024);
        }
        SCHED_FENCE();
    }
    if constexpr (T + 2 < 16) {            // issue x_{T+2} (own buf, read at T-1: safe)
        unsigned char* xd = xw + ((T + 2) % 3) * 2048;
        gload_lds16(xsrc + (T + 2) * 32, xd);
        gload_lds16(xsrc + (T + 2) * 32 + 8 * KD, xd + 1024);
    }
    SCHED_FENCE();
    vmwait<(T <= 13) ? 6 : ((T == 14) ? 2 : 0)>();   // retire x_T only
    SCHED_FENCE();

    const unsigned char* xbf = xw + (T % 3) * 2048;
    f32x4 va = *reinterpret_cast<const f32x4*>(xbf + va_off);
    f32x4 vb = *reinterpret_cast<const f32x4*>(xbf + (va_off ^ 16));
    bf16x8 ah, al;
    cvt8(va, vb, ah, al);

    const unsigned char* bb = bB + ((T >> 1) & 1) * 16384;
    const int bo = (T & 1) ? bo1 : bo0;
    bf16x8 b0 = *reinterpret_cast<const bf16x8*>(bb + bo);
    bf16x8 b1 = *reinterpret_cast<const bf16x8*>(bb + bo + 2048);
    bf16x8 b2 = *reinterpret_cast<const bf16x8*>(bb + bo + 4096);
    bf16x8 b3 = *reinterpret_cast<const bf16x8*>(bb + bo + 6144);
    acc[0] = MFMA_B16(ah, b0, acc[0]);
    acc[1] = MFMA_B16(ah, b1, acc[1]);
    acc[2] = MFMA_B16(ah, b2, acc[2]);
    acc[3] = MFMA_B16(ah, b3, acc[3]);
    acc[0] = MFMA_B16(al, b0, acc[0]);
    acc[1] = MFMA_B16(al, b1, acc[1]);
    acc[2] = MFMA_B16(al, b2, acc[2]);
    acc[3] = MFMA_B16(al, b3, acc[3]);
    b0 = *reinterpret_cast<const bf16x8*>(bb + 8192 + bo);         // lo plane
    b1 = *reinterpret_cast<const bf16x8*>(bb + 8192 + bo + 2048);
    b2 = *reinterpret_cast<const bf16x8*>(bb + 8192 + bo + 4096);
    b3 = *reinterpret_cast<const bf16x8*>(bb + 8192 + bo + 6144);
    acc[0] = MFMA_B16(ah, b0, acc[0]);
    acc[1] = MFMA_B16(ah, b1, acc[1]);
    acc[2] = MFMA_B16(ah, b2, acc[2]);
    acc[3] = MFMA_B16(ah, b3, acc[3]);

    if constexpr (T + 1 < 16)
        tiles<T + 1>(xsrc, bsrc, xw, bB, bdoff, va_off, bo0, bo1, acc);
}

// LDS 80 KB -> 2 blocks/CU = 16 waves/CU = 4 waves/SIMD; VGPR capped 128.
__global__ __launch_bounds__(NT, 4)
void lt_mfma10(const float* __restrict__ x, const unsigned short* __restrict__ ws,
               float* __restrict__ out) {
    __shared__ __align__(16) unsigned char lds[81920];
    unsigned char* bB = lds + B_OFF;

    const int tid  = threadIdx.x;
    const int wave = tid >> 6;
    const int lane = tid & 63;
    const int fr   = lane & 15;
    const int g    = lane >> 4;
    const int r0   = blockIdx.x * BM;

    unsigned char* xw = lds + wave * XB;   // wave-private x triple buffer
    // x DMA source: row = r0 + wave*16 + j*8 + (lane>>3); k-slot pre-swizzled
    const float* xsrc = x + (size_t)(r0 + wave * 16 + (lane >> 3)) * KD
                          + (((lane & 7) ^ ((lane >> 3) & 7)) << 2);
    // B DMA: wave -> plane p = wave>>2, row quarter rq = wave&3 (16 rows, 2 instrs)
    const int p  = wave >> 2;
    const int rq = wave & 3;
    const unsigned short* bsrc = ws + p * 32768
                                    + (size_t)(rq * 16 + (lane >> 3)) * KD
                                    + (((lane & 7) ^ ((lane >> 3) & 7)) << 3);
    const int bdoff = p * 8192 + rq * 2048;
    // frag offsets (slot-swizzled; 2-way bank aliasing = free)
    const int va_off = (fr << 7) + (((2 * g) ^ (fr & 7)) << 4);
    const int bo0    = (fr << 7) + ((g       ^ (fr & 7)) << 4);
    const int bo1    = (fr << 7) + (((4 + g) ^ (fr & 7)) << 4);

    f32x4 acc[4];
#pragma unroll
    for (int j = 0; j < 4; ++j) acc[j] = (f32x4)(0.f);

    // prologue issues (queue = [B_0(2), x_0(2), x_1(2)])
    gload_lds16(bsrc, bB + bdoff);
    gload_lds16(bsrc + 8 * KD, bB + bdoff + 1024);
    gload_lds16(xsrc, xw);
    gload_lds16(xsrc + 8 * KD, xw + 1024);
    gload_lds16(xsrc + 32, xw + 2048);
    gload_lds16(xsrc + 32 + 8 * KD, xw + 3072);
    SCHED_FENCE();

    tiles<0>(xsrc, bsrc, xw, bB, bdoff, va_off, bo0, bo1, acc);

    // ---- epilogue: wave-private (own 6 KB x region), 2 sub-phases of 8 rows
    float* warea = reinterpret_cast<float*>(xw);      // [8][65]  = 2080 B
    float* zw    = warea + 520;                       // [8][127] = 4064 B (16B-aligned)
    const int o  = lane >> 3;                         // row 0..7
    const int p8 = lane & 7;                          // nodes [p8*16, +16)

#pragma unroll
    for (int s = 0; s < 2; ++s) {
        if ((g >> 1) == s) {                          // rows s*8..s*8+7 live in g={2s,2s+1}
#pragma unroll
            for (int nf = 0; nf < 4; ++nf)
#pragma unroll
                for (int rg = 0; rg < 4; ++rg)
                    warea[((g & 1) * 4 + rg) * 65 + nf * 16 + fr] = acc[nf][rg];
        }
        // same-wave LDS ordering via lgkmcnt; no barriers anywhere in epilogue
        const float* srow = warea + o * 65;
        float* zrow = zw + o * NNODES;
        if (p8 == 0) zrow[0] = 1.f;
        tree_walk8<0>(1.f, srow, zrow, p8);

        float* og = out + (size_t)(r0 + wave * 16 + s * 8) * NNODES;  // 16B-aligned
#pragma unroll
        for (int j = 0; j < 4; ++j) {
            const int idx = j * 64 + lane;
            if (idx < 254)
                *reinterpret_cast<f32x4*>(og + idx * 4) =
                    *reinterpret_cast<const f32x4*>(zw + idx * 4);
        }
    }
}

extern "C" void kernel_launch(void* const* d_in, const int* in_sizes, int n_in,
                              void* d_out, int out_size, void* d_ws, size_t ws_size,
                              hipStream_t stream) {
    const float* x = (const float*)d_in[0];          // [131072, 512]
    const float* A = (const float*)d_in[1];          // [63, 512]
    float* out = (float*)d_out;                      // [131072, 127]
    unsigned short* ws = (unsigned short*)d_ws;      // 128 KB: B bf16 hi/lo planes
    const int nrows = in_sizes[0] / KD;              // 131072
    lt_prep<<<dim3(32), dim3(256), 0, stream>>>(A, ws);
    lt_mfma10<<<dim3(nrows / BM), dim3(NT), 0, stream>>>(x, ws, out);
}